// Round 1
// baseline (517.541 us; speedup 1.0000x reference)
//
#include <hip/hip_runtime.h>
#include <math.h>

#define EMB 128
#define NH 8
#define DH 16
#define HID 256
#define NODE 1000
#define PATCH 196
#define NKEY (NODE + PATCH)   // 1196
#define BB 8
#define POMO 1000
#define KT 16                  // attention key tile

__device__ __forceinline__ float tanh10(float x) {
    // 10*tanh(x), overflow-safe: e->inf gives 10, e->0 gives -10
    float e = __expf(2.0f * x);
    return 10.0f * (1.0f - 2.0f / (e + 1.0f));
}

// ---------------- hypernet: pref -> 5 weight matrices (128x128 each) --------
__global__ __launch_bounds__(256) void hyper_kernel(
    const float* __restrict__ pref,
    const float* __restrict__ fc1_w, const float* __restrict__ fc1_b,
    const float* __restrict__ fc2_w, const float* __restrict__ fc2_b,
    const float* __restrict__ fc3_w, const float* __restrict__ fc3_b,
    const float* __restrict__ wqf, const float* __restrict__ wql,
    const float* __restrict__ wk,  const float* __restrict__ wv,
    const float* __restrict__ wc,  float* __restrict__ W5)
{
    __shared__ float h1[HID];
    __shared__ float h2[HID];
    __shared__ float mid[16];
    int t = threadIdx.x;
    float p0 = pref[0], p1 = pref[1], p2 = pref[2];
    h1[t] = fc1_b[t] + p0 * fc1_w[t * 3 + 0] + p1 * fc1_w[t * 3 + 1] + p2 * fc1_w[t * 3 + 2];
    __syncthreads();
    {
        float s = fc2_b[t];
        for (int j = 0; j < HID; ++j) s += h1[j] * fc2_w[t * HID + j];
        h2[t] = s;
    }
    __syncthreads();
    if (t < 15) {
        float m = fc3_b[t];
        for (int j = 0; j < HID; ++j) m += h2[j] * fc3_w[t * HID + j];
        mid[t] = m;
    }
    __syncthreads();
    #pragma unroll
    for (int mat = 0; mat < 5; ++mat) {
        const float* w = (mat == 0) ? wqf : (mat == 1) ? wql : (mat == 2) ? wk : (mat == 3) ? wv : wc;
        float m0 = mid[mat * 3 + 0], m1 = mid[mat * 3 + 1], m2 = mid[mat * 3 + 2];
        for (int x = t; x < EMB * EMB; x += 256) {
            W5[mat * EMB * EMB + x] = m0 * w[x * 3 + 0] + m1 * w[x * 3 + 1] + m2 * w[x * 3 + 2];
        }
    }
}

// ---------------- K,V projection of encoded_nodes ---------------------------
// 32 rows per block; thread o in [0,256): o<128 -> K col o, else V col o-128.
__global__ __launch_bounds__(256) void kv_proj_kernel(
    const float* __restrict__ nodes, const float* __restrict__ W5,
    float* __restrict__ Kb, float* __restrict__ Vb)
{
    __shared__ float xs[32][EMB];
    int t = threadIdx.x;
    long r0 = (long)blockIdx.x * 32;            // over BB*NKEY = 9568 (299*32 exact)
    const float4* s4 = (const float4*)(nodes + r0 * EMB);
    float4* x4p = (float4*)&xs[0][0];
    for (int i = t; i < 32 * EMB / 4; i += 256) x4p[i] = s4[i];
    __syncthreads();
    int o = t;
    const float* W = (o < EMB) ? (W5 + 2 * EMB * EMB + o * EMB)
                               : (W5 + 3 * EMB * EMB + (o - EMB) * EMB);
    float acc[32];
    #pragma unroll
    for (int r = 0; r < 32; ++r) acc[r] = 0.f;
    for (int e = 0; e < EMB; e += 4) {
        float4 w4 = *(const float4*)&W[e];
        #pragma unroll
        for (int r = 0; r < 32; ++r) {
            float4 x4 = *(const float4*)&xs[r][e];
            acc[r] += x4.x * w4.x + x4.y * w4.y + x4.z * w4.z + x4.w * w4.w;
        }
    }
    float* dst = (o < EMB) ? (Kb + r0 * EMB + o) : (Vb + r0 * EMB + (o - EMB));
    #pragma unroll
    for (int r = 0; r < 32; ++r) dst[(long)r * EMB] = acc[r];
}

// ---------------- Q projection: q1@Wqf.T + last@Wql.T -----------------------
__global__ __launch_bounds__(256) void q_proj_kernel(
    const float* __restrict__ q1, const float* __restrict__ lastn,
    const float* __restrict__ W5, float* __restrict__ Qb)
{
    __shared__ float xa[32][EMB];
    __shared__ float xb[32][EMB];
    int t = threadIdx.x;
    long r0 = (long)blockIdx.x * 32;            // over 8000 (250*32 exact)
    const float4* a4 = (const float4*)(q1 + r0 * EMB);
    const float4* b4 = (const float4*)(lastn + r0 * EMB);
    float4* xap = (float4*)&xa[0][0];
    float4* xbp = (float4*)&xb[0][0];
    for (int i = t; i < 32 * EMB / 4; i += 256) { xap[i] = a4[i]; xbp[i] = b4[i]; }
    __syncthreads();
    int o = t & 127;
    int rbase = (t >> 7) * 16;
    const float* Wf = W5 + 0 * EMB * EMB + o * EMB;
    const float* Wl = W5 + 1 * EMB * EMB + o * EMB;
    float acc[16];
    #pragma unroll
    for (int r = 0; r < 16; ++r) acc[r] = 0.f;
    for (int e = 0; e < EMB; e += 4) {
        float4 wf = *(const float4*)&Wf[e];
        float4 wl = *(const float4*)&Wl[e];
        #pragma unroll
        for (int r = 0; r < 16; ++r) {
            float4 va = *(const float4*)&xa[rbase + r][e];
            float4 vb = *(const float4*)&xb[rbase + r][e];
            acc[r] += va.x * wf.x + va.y * wf.y + va.z * wf.z + va.w * wf.w
                    + vb.x * wl.x + vb.y * wl.y + vb.z * wl.z + vb.w * wl.w;
        }
    }
    #pragma unroll
    for (int r = 0; r < 16; ++r) Qb[(r0 + rbase + r) * EMB + o] = acc[r];
}

// ---------------- fused masked MHA (flash-style, all heads per block) -------
// grid (8, 63): blockIdx.x = b (XCD-aligned), blockIdx.y = 16-row tile.
// block 128 threads: h = t>>4, r = t&15. One query row per thread per head.
__global__ __launch_bounds__(128) void attn_kernel(
    const float* __restrict__ Kb, const float* __restrict__ Vb,
    const float* __restrict__ Qb, const float* __restrict__ mask,
    float* __restrict__ OC)
{
    __shared__ float ks[KT][EMB];
    __shared__ float vs[KT][EMB];
    __shared__ float ms[16][KT + 1];
    int t = threadIdx.x;
    int b = blockIdx.x;
    int tile = blockIdx.y;
    int r = t & 15;
    int h = t >> 4;
    int row = tile * 16 + r;
    bool active = row < POMO;

    float q[DH];
    #pragma unroll
    for (int i = 0; i < DH; ++i) q[i] = 0.f;
    if (active) {
        const float4* qp = (const float4*)(Qb + ((long)b * POMO + row) * EMB + h * DH);
        #pragma unroll
        for (int i = 0; i < 4; ++i) {
            float4 v = qp[i];
            q[4 * i + 0] = v.x; q[4 * i + 1] = v.y; q[4 * i + 2] = v.z; q[4 * i + 3] = v.w;
        }
    }
    float acc[DH];
    #pragma unroll
    for (int i = 0; i < DH; ++i) acc[i] = 0.f;
    float m_run = -1e30f, l_run = 0.f;

    for (int m0 = 0; m0 < NKEY; m0 += KT) {
        __syncthreads();
        // stage K,V tile (zero-fill past NKEY)
        {
            const float4* ksrc = (const float4*)(Kb + ((long)b * NKEY + m0) * EMB);
            const float4* vsrc = (const float4*)(Vb + ((long)b * NKEY + m0) * EMB);
            float4* kd = (float4*)&ks[0][0];
            float4* vd = (float4*)&vs[0][0];
            int nvalid4 = (NKEY - m0 < KT ? NKEY - m0 : KT) * (EMB / 4);
            for (int i = t; i < KT * EMB / 4; i += 128) {
                float4 z = make_float4(0.f, 0.f, 0.f, 0.f);
                kd[i] = (i < nvalid4) ? ksrc[i] : z;
                vd[i] = (i < nvalid4) ? vsrc[i] : z;
            }
            // stage mask tile (16 rows x KT keys); zero for patch keys / inactive rows
            for (int i = t; i < 16 * KT; i += 128) {
                int rr = i >> 4;
                int j = i & 15;
                int key = m0 + j;
                int grow = tile * 16 + rr;
                float mv = 0.f;
                if (key < NODE && grow < POMO)
                    mv = mask[((long)b * POMO + grow) * NODE + key];
                ms[rr][j] = mv;
            }
        }
        __syncthreads();

        float sc[KT];
        #pragma unroll
        for (int j = 0; j < KT; ++j) {
            float s = 0.f;
            #pragma unroll
            for (int e = 0; e < DH; e += 4) {
                float4 k4 = *(const float4*)&ks[j][h * DH + e];
                s += q[e] * k4.x + q[e + 1] * k4.y + q[e + 2] * k4.z + q[e + 3] * k4.w;
            }
            s = s * 0.25f + ms[r][j];
            if (m0 + j >= NKEY) s = -1e30f;
            sc[j] = s;
        }
        float tmax = sc[0];
        #pragma unroll
        for (int j = 1; j < KT; ++j) tmax = fmaxf(tmax, sc[j]);
        float new_m = fmaxf(m_run, tmax);
        float scale = __expf(m_run - new_m);
        m_run = new_m;
        l_run *= scale;
        #pragma unroll
        for (int d = 0; d < DH; ++d) acc[d] *= scale;
        #pragma unroll
        for (int j = 0; j < KT; ++j) {
            float p = __expf(sc[j] - new_m);
            l_run += p;
            #pragma unroll
            for (int e = 0; e < DH; e += 4) {
                float4 v4 = *(const float4*)&vs[j][h * DH + e];
                acc[e + 0] += p * v4.x; acc[e + 1] += p * v4.y;
                acc[e + 2] += p * v4.z; acc[e + 3] += p * v4.w;
            }
        }
    }
    if (active) {
        float inv = 1.0f / l_run;
        float* op = OC + ((long)b * POMO + row) * EMB + h * DH;
        #pragma unroll
        for (int d = 0; d < DH; ++d) op[d] = acc[d] * inv;
    }
}

// ---------------- multi-head combine: mh = oc @ Wc.T ------------------------
__global__ __launch_bounds__(256) void combine_kernel(
    const float* __restrict__ OC, const float* __restrict__ W5,
    float* __restrict__ MH)
{
    __shared__ float xs[32][EMB];
    int t = threadIdx.x;
    long r0 = (long)blockIdx.x * 32;            // over 8000
    const float4* s4 = (const float4*)(OC + r0 * EMB);
    float4* xp = (float4*)&xs[0][0];
    for (int i = t; i < 32 * EMB / 4; i += 256) xp[i] = s4[i];
    __syncthreads();
    int o = t & 127;
    int rbase = (t >> 7) * 16;
    const float* W = W5 + 4 * EMB * EMB + o * EMB;
    float acc[16];
    #pragma unroll
    for (int r = 0; r < 16; ++r) acc[r] = 0.f;
    for (int e = 0; e < EMB; e += 4) {
        float4 w4 = *(const float4*)&W[e];
        #pragma unroll
        for (int r = 0; r < 16; ++r) {
            float4 x4 = *(const float4*)&xs[rbase + r][e];
            acc[r] += x4.x * w4.x + x4.y * w4.y + x4.z * w4.z + x4.w * w4.w;
        }
    }
    #pragma unroll
    for (int r = 0; r < 16; ++r) MH[(r0 + rbase + r) * EMB + o] = acc[r];
}

// ---------------- logits: 10*tanh((mh @ nodes.T)/sqrt(128)) + mask ----------
// grid (8, 16, 16): x=b (XCD-aligned), y=m-tile, z=n-tile. 64x64 tile, K=128.
__global__ __launch_bounds__(256) void logits_kernel(
    const float* __restrict__ MH, const float* __restrict__ nodes,
    const float* __restrict__ mask, float* __restrict__ out)
{
    __shared__ float As[64][65];   // [e][r]
    __shared__ float Bs[64][65];   // [e][c]
    int t = threadIdx.x;
    int b = blockIdx.x;
    int m0 = blockIdx.y * 64;
    int n0 = blockIdx.z * 64;
    int tc = t & 15, tr = t >> 4;
    float acc[4][4];
    #pragma unroll
    for (int i = 0; i < 4; ++i)
        #pragma unroll
        for (int j = 0; j < 4; ++j) acc[i][j] = 0.f;

    for (int e0 = 0; e0 < EMB; e0 += 64) {
        for (int i = t; i < 4096; i += 256) {
            int rr = i >> 6, e = i & 63;
            int n = n0 + rr;
            As[e][rr] = (n < POMO) ? MH[((long)b * POMO + n) * EMB + e0 + e] : 0.f;
        }
        for (int i = t; i < 4096; i += 256) {
            int cc = i >> 6, e = i & 63;
            Bs[e][cc] = nodes[((long)b * NKEY + m0 + cc) * EMB + e0 + e];
        }
        __syncthreads();
        for (int e = 0; e < 64; ++e) {
            float a0 = As[e][tr * 4 + 0], a1 = As[e][tr * 4 + 1];
            float a2 = As[e][tr * 4 + 2], a3 = As[e][tr * 4 + 3];
            float b0 = Bs[e][tc * 4 + 0], b1 = Bs[e][tc * 4 + 1];
            float b2 = Bs[e][tc * 4 + 2], b3 = Bs[e][tc * 4 + 3];
            acc[0][0] += a0 * b0; acc[0][1] += a0 * b1; acc[0][2] += a0 * b2; acc[0][3] += a0 * b3;
            acc[1][0] += a1 * b0; acc[1][1] += a1 * b1; acc[1][2] += a1 * b2; acc[1][3] += a1 * b3;
            acc[2][0] += a2 * b0; acc[2][1] += a2 * b1; acc[2][2] += a2 * b2; acc[2][3] += a2 * b3;
            acc[3][0] += a3 * b0; acc[3][1] += a3 * b1; acc[3][2] += a3 * b2; acc[3][3] += a3 * b3;
        }
        __syncthreads();
    }
    const float inv = 0.08838834764831845f;  // 1/sqrt(128)
    #pragma unroll
    for (int i = 0; i < 4; ++i) {
        int n = n0 + tr * 4 + i;
        if (n >= POMO) continue;
        #pragma unroll
        for (int j = 0; j < 4; ++j) {
            int m = m0 + tc * 4 + j;
            if (m >= NODE) continue;
            long idx = ((long)b * POMO + n) * NODE + m;
            out[idx] = tanh10(acc[i][j] * inv) + mask[idx];
        }
    }
}

// ---------------- in-place row softmax over 1000 ----------------------------
__global__ __launch_bounds__(256) void softmax_kernel(float* __restrict__ out)
{
    __shared__ float red[256];
    int t = threadIdx.x;
    float* p = out + (long)blockIdx.x * NODE;
    bool act = t < 250;
    float4 x = make_float4(0.f, 0.f, 0.f, 0.f);
    if (act) x = *(const float4*)&p[t * 4];
    float mx = act ? fmaxf(fmaxf(x.x, x.y), fmaxf(x.z, x.w)) : -1e30f;
    red[t] = mx;
    __syncthreads();
    #pragma unroll
    for (int s = 128; s >= 1; s >>= 1) {
        if (t < s) red[t] = fmaxf(red[t], red[t + s]);
        __syncthreads();
    }
    float M = red[0];
    __syncthreads();
    float4 e;
    e.x = __expf(x.x - M); e.y = __expf(x.y - M);
    e.z = __expf(x.z - M); e.w = __expf(x.w - M);
    red[t] = act ? (e.x + e.y + e.z + e.w) : 0.f;
    __syncthreads();
    #pragma unroll
    for (int s = 128; s >= 1; s >>= 1) {
        if (t < s) red[t] += red[t + s];
        __syncthreads();
    }
    float inv = 1.0f / red[0];
    if (act) {
        float4 rr;
        rr.x = e.x * inv; rr.y = e.y * inv; rr.z = e.z * inv; rr.w = e.w * inv;
        *(float4*)&p[t * 4] = rr;
    }
}

extern "C" void kernel_launch(void* const* d_in, const int* in_sizes, int n_in,
                              void* d_out, int out_size, void* d_ws, size_t ws_size,
                              hipStream_t stream)
{
    const float* pref  = (const float*)d_in[0];
    const float* nodes = (const float*)d_in[1];
    const float* q1    = (const float*)d_in[2];
    const float* lastn = (const float*)d_in[3];
    const float* mask  = (const float*)d_in[4];
    const float* fc1_w = (const float*)d_in[5];
    const float* fc1_b = (const float*)d_in[6];
    const float* fc2_w = (const float*)d_in[7];
    const float* fc2_b = (const float*)d_in[8];
    const float* fc3_w = (const float*)d_in[9];
    const float* fc3_b = (const float*)d_in[10];
    const float* wqf   = (const float*)d_in[11];
    const float* wql   = (const float*)d_in[12];
    const float* wk    = (const float*)d_in[13];
    const float* wv    = (const float*)d_in[14];
    const float* wc    = (const float*)d_in[15];
    float* out = (float*)d_out;
    float* ws  = (float*)d_ws;

    float* W5 = ws;                                   // 5*16384 = 81920
    float* Kb = ws + 81920;                           // 8*1196*128
    float* Vb = Kb + (long)BB * NKEY * EMB;
    float* Qb = Vb + (long)BB * NKEY * EMB;           // 8*1000*128
    float* OC = Qb + (long)BB * POMO * EMB;
    float* MH = OC + (long)BB * POMO * EMB;           // ends at ~22.4 MB

    hipLaunchKernelGGL(hyper_kernel, dim3(1), dim3(256), 0, stream,
                       pref, fc1_w, fc1_b, fc2_w, fc2_b, fc3_w, fc3_b,
                       wqf, wql, wk, wv, wc, W5);
    hipLaunchKernelGGL(kv_proj_kernel, dim3(299), dim3(256), 0, stream, nodes, W5, Kb, Vb);
    hipLaunchKernelGGL(q_proj_kernel, dim3(250), dim3(256), 0, stream, q1, lastn, W5, Qb);
    hipLaunchKernelGGL(attn_kernel, dim3(8, 63), dim3(128), 0, stream, Kb, Vb, Qb, mask, OC);
    hipLaunchKernelGGL(combine_kernel, dim3(250), dim3(256), 0, stream, OC, W5, MH);
    hipLaunchKernelGGL(logits_kernel, dim3(8, 16, 16), dim3(256), 0, stream, MH, nodes, mask, out);
    hipLaunchKernelGGL(softmax_kernel, dim3(8000), dim3(256), 0, stream, out);
}

// Round 2
// 371.184 us; speedup vs baseline: 1.3943x; 1.3943x over previous
//
#include <hip/hip_runtime.h>
#include <math.h>

#define EMB 128
#define NH 8
#define DH 16
#define HID 256
#define NODE 1000
#define PATCH 196
#define NKEY (NODE + PATCH)   // 1196
#define BB 8
#define POMO 1000
#define KT 16                  // attention key tile
#define SCH 6                  // key-split chunks
#define CKEYS 200              // keys per chunk (last chunk = 196)
#define RTILES 32              // row tiles of 32 rows
#define PREC 20                // floats per partial record (16 acc + m + l + pad)

__device__ __forceinline__ float tanh10(float x) {
    float e = __expf(2.0f * x);
    return 10.0f * (1.0f - 2.0f / (e + 1.0f));
}

// ---------------- hypernet: pref -> 5 weight matrices (128x128 each) --------
__global__ __launch_bounds__(256) void hyper_kernel(
    const float* __restrict__ pref,
    const float* __restrict__ fc1_w, const float* __restrict__ fc1_b,
    const float* __restrict__ fc2_w, const float* __restrict__ fc2_b,
    const float* __restrict__ fc3_w, const float* __restrict__ fc3_b,
    const float* __restrict__ wqf, const float* __restrict__ wql,
    const float* __restrict__ wk,  const float* __restrict__ wv,
    const float* __restrict__ wc,  float* __restrict__ W5)
{
    __shared__ float h1[HID];
    __shared__ float h2[HID];
    __shared__ float mid[16];
    int t = threadIdx.x;
    float p0 = pref[0], p1 = pref[1], p2 = pref[2];
    h1[t] = fc1_b[t] + p0 * fc1_w[t * 3 + 0] + p1 * fc1_w[t * 3 + 1] + p2 * fc1_w[t * 3 + 2];
    __syncthreads();
    {
        float s = fc2_b[t];
        for (int j = 0; j < HID; ++j) s += h1[j] * fc2_w[t * HID + j];
        h2[t] = s;
    }
    __syncthreads();
    if (t < 15) {
        float m = fc3_b[t];
        for (int j = 0; j < HID; ++j) m += h2[j] * fc3_w[t * HID + j];
        mid[t] = m;
    }
    __syncthreads();
    #pragma unroll
    for (int mat = 0; mat < 5; ++mat) {
        const float* w = (mat == 0) ? wqf : (mat == 1) ? wql : (mat == 2) ? wk : (mat == 3) ? wv : wc;
        float m0 = mid[mat * 3 + 0], m1 = mid[mat * 3 + 1], m2 = mid[mat * 3 + 2];
        for (int x = t; x < EMB * EMB; x += 256) {
            W5[mat * EMB * EMB + x] = m0 * w[x * 3 + 0] + m1 * w[x * 3 + 1] + m2 * w[x * 3 + 2];
        }
    }
}

// ---------------- K,V projection of encoded_nodes ---------------------------
__global__ __launch_bounds__(256) void kv_proj_kernel(
    const float* __restrict__ nodes, const float* __restrict__ W5,
    float* __restrict__ Kb, float* __restrict__ Vb)
{
    __shared__ float xs[32][EMB];
    int t = threadIdx.x;
    long r0 = (long)blockIdx.x * 32;            // over BB*NKEY = 9568 (299*32 exact)
    const float4* s4 = (const float4*)(nodes + r0 * EMB);
    float4* x4p = (float4*)&xs[0][0];
    for (int i = t; i < 32 * EMB / 4; i += 256) x4p[i] = s4[i];
    __syncthreads();
    int o = t;
    const float* W = (o < EMB) ? (W5 + 2 * EMB * EMB + o * EMB)
                               : (W5 + 3 * EMB * EMB + (o - EMB) * EMB);
    float acc[32];
    #pragma unroll
    for (int r = 0; r < 32; ++r) acc[r] = 0.f;
    for (int e = 0; e < EMB; e += 4) {
        float4 w4 = *(const float4*)&W[e];
        #pragma unroll
        for (int r = 0; r < 32; ++r) {
            float4 x4 = *(const float4*)&xs[r][e];
            acc[r] += x4.x * w4.x + x4.y * w4.y + x4.z * w4.z + x4.w * w4.w;
        }
    }
    float* dst = (o < EMB) ? (Kb + r0 * EMB + o) : (Vb + r0 * EMB + (o - EMB));
    #pragma unroll
    for (int r = 0; r < 32; ++r) dst[(long)r * EMB] = acc[r];
}

// ---------------- Q projection: q1@Wqf.T + last@Wql.T -----------------------
__global__ __launch_bounds__(256) void q_proj_kernel(
    const float* __restrict__ q1, const float* __restrict__ lastn,
    const float* __restrict__ W5, float* __restrict__ Qb)
{
    __shared__ float xa[32][EMB];
    __shared__ float xb[32][EMB];
    int t = threadIdx.x;
    long r0 = (long)blockIdx.x * 32;            // over 8000 (250*32 exact)
    const float4* a4 = (const float4*)(q1 + r0 * EMB);
    const float4* b4 = (const float4*)(lastn + r0 * EMB);
    float4* xap = (float4*)&xa[0][0];
    float4* xbp = (float4*)&xb[0][0];
    for (int i = t; i < 32 * EMB / 4; i += 256) { xap[i] = a4[i]; xbp[i] = b4[i]; }
    __syncthreads();
    int o = t & 127;
    int rbase = (t >> 7) * 16;
    const float* Wf = W5 + 0 * EMB * EMB + o * EMB;
    const float* Wl = W5 + 1 * EMB * EMB + o * EMB;
    float acc[16];
    #pragma unroll
    for (int r = 0; r < 16; ++r) acc[r] = 0.f;
    for (int e = 0; e < EMB; e += 4) {
        float4 wf = *(const float4*)&Wf[e];
        float4 wl = *(const float4*)&Wl[e];
        #pragma unroll
        for (int r = 0; r < 16; ++r) {
            float4 va = *(const float4*)&xa[rbase + r][e];
            float4 vb = *(const float4*)&xb[rbase + r][e];
            acc[r] += va.x * wf.x + va.y * wf.y + va.z * wf.z + va.w * wf.w
                    + vb.x * wl.x + vb.y * wl.y + vb.z * wl.z + vb.w * wl.w;
        }
    }
    #pragma unroll
    for (int r = 0; r < 16; ++r) Qb[(r0 + rbase + r) * EMB + o] = acc[r];
}

// ---------------- fused masked MHA, key-split flash -------------------------
// grid (8, 32, 6): x=b (XCD-aligned), y=32-row tile, z=key chunk.
// block 128: h = t>>4, rr = t&15; each thread owns rows {2rr, 2rr+1} of the tile.
// Partials {acc[16], m, l} per (row, head, chunk) go to `part` (aliases d_out).
__global__ __launch_bounds__(128, 3) void attn_split_kernel(
    const float* __restrict__ Kb, const float* __restrict__ Vb,
    const float* __restrict__ Qb, const float* __restrict__ mask,
    float* __restrict__ part)
{
    __shared__ float ks[KT][EMB];
    __shared__ float vs[KT][EMB];
    int t = threadIdx.x;
    int b = blockIdx.x;
    int tile = blockIdx.y;
    int c = blockIdx.z;
    int rr = t & 15;
    int h = t >> 4;
    int row0 = tile * 32 + rr * 2;
    bool active = row0 < POMO;       // row0 even => row0+1 also < POMO when active
    int kstart = c * CKEYS;
    int kend = kstart + CKEYS; if (kend > NKEY) kend = NKEY;
    bool has_mask = (kstart < NODE); // chunks 0..4 are node keys, chunk 5 pure patch

    float q0[DH], q1r[DH], acc0[DH], acc1[DH];
    #pragma unroll
    for (int i = 0; i < DH; ++i) { q0[i] = 0.f; q1r[i] = 0.f; acc0[i] = 0.f; acc1[i] = 0.f; }
    if (active) {
        const float4* qp0 = (const float4*)(Qb + ((long)b * POMO + row0) * EMB + h * DH);
        const float4* qp1 = (const float4*)(Qb + ((long)b * POMO + row0 + 1) * EMB + h * DH);
        #pragma unroll
        for (int i = 0; i < 4; ++i) {
            float4 v = qp0[i];   // pre-scale by 1/sqrt(16) so score = q.k + mask
            q0[4*i+0] = v.x*0.25f; q0[4*i+1] = v.y*0.25f; q0[4*i+2] = v.z*0.25f; q0[4*i+3] = v.w*0.25f;
            float4 w = qp1[i];
            q1r[4*i+0] = w.x*0.25f; q1r[4*i+1] = w.y*0.25f; q1r[4*i+2] = w.z*0.25f; q1r[4*i+3] = w.w*0.25f;
        }
    }
    float m0_run = -1e30f, m1_run = -1e30f, l0 = 0.f, l1 = 0.f;

    for (int t0 = kstart; t0 < kend; t0 += KT) {
        int valid = kend - t0; if (valid > KT) valid = KT;
        __syncthreads();
        {   // stage K,V tile
            const float4* ksrc = (const float4*)(Kb + ((long)b * NKEY + t0) * EMB);
            const float4* vsrc = (const float4*)(Vb + ((long)b * NKEY + t0) * EMB);
            float4* kd = (float4*)&ks[0][0];
            float4* vd = (float4*)&vs[0][0];
            int nv4 = valid * (EMB / 4);
            for (int i = t; i < KT * EMB / 4; i += 128) {
                float4 z = make_float4(0.f, 0.f, 0.f, 0.f);
                kd[i] = (i < nv4) ? ksrc[i] : z;
                vd[i] = (i < nv4) ? vsrc[i] : z;
            }
        }
        __syncthreads();

        float sc0[KT], sc1[KT];
        // init scores with mask (global float4 reads; no LDS)
        if (has_mask && active) {
            const float4* mp0 = (const float4*)(mask + ((long)b * POMO + row0) * NODE + t0);
            const float4* mp1 = (const float4*)(mask + ((long)b * POMO + row0 + 1) * NODE + t0);
            int mv4 = valid >> 2;   // valid in {16,8} here
            #pragma unroll
            for (int j4 = 0; j4 < KT / 4; ++j4) {
                float4 a = (j4 < mv4) ? mp0[j4] : make_float4(0,0,0,0);
                float4 bm = (j4 < mv4) ? mp1[j4] : make_float4(0,0,0,0);
                sc0[4*j4+0] = a.x;  sc0[4*j4+1] = a.y;  sc0[4*j4+2] = a.z;  sc0[4*j4+3] = a.w;
                sc1[4*j4+0] = bm.x; sc1[4*j4+1] = bm.y; sc1[4*j4+2] = bm.z; sc1[4*j4+3] = bm.w;
            }
        } else {
            #pragma unroll
            for (int j = 0; j < KT; ++j) { sc0[j] = 0.f; sc1[j] = 0.f; }
        }
        // scores: one K read serves both rows
        #pragma unroll
        for (int j = 0; j < KT; ++j) {
            float s0 = sc0[j], s1 = sc1[j];
            #pragma unroll
            for (int e = 0; e < DH; e += 4) {
                float4 k4 = *(const float4*)&ks[j][h * DH + e];
                s0 += q0[e]*k4.x + q0[e+1]*k4.y + q0[e+2]*k4.z + q0[e+3]*k4.w;
                s1 += q1r[e]*k4.x + q1r[e+1]*k4.y + q1r[e+2]*k4.z + q1r[e+3]*k4.w;
            }
            sc0[j] = (j < valid) ? s0 : -1e30f;
            sc1[j] = (j < valid) ? s1 : -1e30f;
        }
        float tm0 = sc0[0], tm1 = sc1[0];
        #pragma unroll
        for (int j = 1; j < KT; ++j) { tm0 = fmaxf(tm0, sc0[j]); tm1 = fmaxf(tm1, sc1[j]); }
        float nm0 = fmaxf(m0_run, tm0), nm1 = fmaxf(m1_run, tm1);
        if (__any((nm0 > m0_run) || (nm1 > m1_run))) {
            float s0f = __expf(m0_run - nm0), s1f = __expf(m1_run - nm1);
            l0 *= s0f; l1 *= s1f;
            #pragma unroll
            for (int d = 0; d < DH; ++d) { acc0[d] *= s0f; acc1[d] *= s1f; }
            m0_run = nm0; m1_run = nm1;
        }
        #pragma unroll
        for (int j = 0; j < KT; ++j) {
            float p0 = __expf(sc0[j] - m0_run);
            float p1 = __expf(sc1[j] - m1_run);
            l0 += p0; l1 += p1;
            #pragma unroll
            for (int e = 0; e < DH; e += 4) {
                float4 v4 = *(const float4*)&vs[j][h * DH + e];
                acc0[e+0] += p0*v4.x; acc0[e+1] += p0*v4.y; acc0[e+2] += p0*v4.z; acc0[e+3] += p0*v4.w;
                acc1[e+0] += p1*v4.x; acc1[e+1] += p1*v4.y; acc1[e+2] += p1*v4.z; acc1[e+3] += p1*v4.w;
            }
        }
    }
    if (active) {
        long rec0 = ((((long)(b * RTILES + tile) * SCH + c) * 32 + rr * 2) * NH + h) * PREC;
        long rec1 = rec0 + (long)NH * PREC;
        #pragma unroll
        for (int i = 0; i < 4; ++i) {
            *(float4*)&part[rec0 + 4*i] = make_float4(acc0[4*i], acc0[4*i+1], acc0[4*i+2], acc0[4*i+3]);
            *(float4*)&part[rec1 + 4*i] = make_float4(acc1[4*i], acc1[4*i+1], acc1[4*i+2], acc1[4*i+3]);
        }
        part[rec0 + 16] = m0_run; part[rec0 + 17] = l0;
        part[rec1 + 16] = m1_run; part[rec1 + 17] = l1;
    }
}

// ---------------- merge key-split partials -> OC ----------------------------
__global__ __launch_bounds__(256) void attn_merge_kernel(
    const float* __restrict__ part, float* __restrict__ OC)
{
    int t = threadIdx.x;          // t = rt*8 + h
    int b = blockIdx.x, tile = blockIdx.y;
    int rt = t >> 3, h = t & 7;
    int row = tile * 32 + rt;
    if (row >= POMO) return;
    const long cs = (long)32 * NH * PREC;   // chunk stride
    long base = (long)(b * RTILES + tile) * SCH * cs + (long)t * PREC;
    float mc[SCH], lc[SCH];
    float M = -1e30f;
    #pragma unroll
    for (int c = 0; c < SCH; ++c) {
        mc[c] = part[base + c * cs + 16];
        lc[c] = part[base + c * cs + 17];
        M = fmaxf(M, mc[c]);
    }
    float L = 0.f;
    float o[16];
    #pragma unroll
    for (int i = 0; i < 16; ++i) o[i] = 0.f;
    #pragma unroll
    for (int c = 0; c < SCH; ++c) {
        float w = __expf(mc[c] - M);
        L += lc[c] * w;
        #pragma unroll
        for (int i4 = 0; i4 < 4; ++i4) {
            float4 a = *(const float4*)&part[base + c * cs + 4 * i4];
            o[4*i4+0] += w*a.x; o[4*i4+1] += w*a.y; o[4*i4+2] += w*a.z; o[4*i4+3] += w*a.w;
        }
    }
    float inv = 1.0f / L;
    float* op = OC + ((long)b * POMO + row) * EMB + h * DH;
    #pragma unroll
    for (int i4 = 0; i4 < 4; ++i4)
        *(float4*)&op[4*i4] = make_float4(o[4*i4]*inv, o[4*i4+1]*inv, o[4*i4+2]*inv, o[4*i4+3]*inv);
}

// ---------------- multi-head combine: mh = oc @ Wc.T ------------------------
__global__ __launch_bounds__(256) void combine_kernel(
    const float* __restrict__ OC, const float* __restrict__ W5,
    float* __restrict__ MH)
{
    __shared__ float xs[32][EMB];
    int t = threadIdx.x;
    long r0 = (long)blockIdx.x * 32;            // over 8000
    const float4* s4 = (const float4*)(OC + r0 * EMB);
    float4* xp = (float4*)&xs[0][0];
    for (int i = t; i < 32 * EMB / 4; i += 256) xp[i] = s4[i];
    __syncthreads();
    int o = t & 127;
    int rbase = (t >> 7) * 16;
    const float* W = W5 + 4 * EMB * EMB + o * EMB;
    float acc[16];
    #pragma unroll
    for (int r = 0; r < 16; ++r) acc[r] = 0.f;
    for (int e = 0; e < EMB; e += 4) {
        float4 w4 = *(const float4*)&W[e];
        #pragma unroll
        for (int r = 0; r < 16; ++r) {
            float4 x4 = *(const float4*)&xs[rbase + r][e];
            acc[r] += x4.x * w4.x + x4.y * w4.y + x4.z * w4.z + x4.w * w4.w;
        }
    }
    #pragma unroll
    for (int r = 0; r < 16; ++r) MH[(r0 + rbase + r) * EMB + o] = acc[r];
}

// ---------------- logits: 10*tanh((mh @ nodes.T)/sqrt(128)) + mask ----------
__global__ __launch_bounds__(256) void logits_kernel(
    const float* __restrict__ MH, const float* __restrict__ nodes,
    const float* __restrict__ mask, float* __restrict__ out)
{
    __shared__ float As[64][65];   // [e][r]
    __shared__ float Bs[64][65];   // [e][c]
    int t = threadIdx.x;
    int b = blockIdx.x;
    int m0 = blockIdx.y * 64;
    int n0 = blockIdx.z * 64;
    int tc = t & 15, tr = t >> 4;
    float acc[4][4];
    #pragma unroll
    for (int i = 0; i < 4; ++i)
        #pragma unroll
        for (int j = 0; j < 4; ++j) acc[i][j] = 0.f;

    for (int e0 = 0; e0 < EMB; e0 += 64) {
        for (int i = t; i < 4096; i += 256) {
            int rr = i >> 6, e = i & 63;
            int n = n0 + rr;
            As[e][rr] = (n < POMO) ? MH[((long)b * POMO + n) * EMB + e0 + e] : 0.f;
        }
        for (int i = t; i < 4096; i += 256) {
            int cc = i >> 6, e = i & 63;
            Bs[e][cc] = nodes[((long)b * NKEY + m0 + cc) * EMB + e0 + e];
        }
        __syncthreads();
        for (int e = 0; e < 64; ++e) {
            float a0 = As[e][tr * 4 + 0], a1 = As[e][tr * 4 + 1];
            float a2 = As[e][tr * 4 + 2], a3 = As[e][tr * 4 + 3];
            float b0 = Bs[e][tc * 4 + 0], b1 = Bs[e][tc * 4 + 1];
            float b2 = Bs[e][tc * 4 + 2], b3 = Bs[e][tc * 4 + 3];
            acc[0][0] += a0 * b0; acc[0][1] += a0 * b1; acc[0][2] += a0 * b2; acc[0][3] += a0 * b3;
            acc[1][0] += a1 * b0; acc[1][1] += a1 * b1; acc[1][2] += a1 * b2; acc[1][3] += a1 * b3;
            acc[2][0] += a2 * b0; acc[2][1] += a2 * b1; acc[2][2] += a2 * b2; acc[2][3] += a2 * b3;
            acc[3][0] += a3 * b0; acc[3][1] += a3 * b1; acc[3][2] += a3 * b2; acc[3][3] += a3 * b3;
        }
        __syncthreads();
    }
    const float inv = 0.08838834764831845f;  // 1/sqrt(128)
    #pragma unroll
    for (int i = 0; i < 4; ++i) {
        int n = n0 + tr * 4 + i;
        if (n >= POMO) continue;
        #pragma unroll
        for (int j = 0; j < 4; ++j) {
            int m = m0 + tc * 4 + j;
            if (m >= NODE) continue;
            long idx = ((long)b * POMO + n) * NODE + m;
            out[idx] = tanh10(acc[i][j] * inv) + mask[idx];
        }
    }
}

// ---------------- in-place row softmax over 1000 ----------------------------
__global__ __launch_bounds__(256) void softmax_kernel(float* __restrict__ out)
{
    __shared__ float red[256];
    int t = threadIdx.x;
    float* p = out + (long)blockIdx.x * NODE;
    bool act = t < 250;
    float4 x = make_float4(0.f, 0.f, 0.f, 0.f);
    if (act) x = *(const float4*)&p[t * 4];
    float mx = act ? fmaxf(fmaxf(x.x, x.y), fmaxf(x.z, x.w)) : -1e30f;
    red[t] = mx;
    __syncthreads();
    #pragma unroll
    for (int s = 128; s >= 1; s >>= 1) {
        if (t < s) red[t] = fmaxf(red[t], red[t + s]);
        __syncthreads();
    }
    float M = red[0];
    __syncthreads();
    float4 e;
    e.x = __expf(x.x - M); e.y = __expf(x.y - M);
    e.z = __expf(x.z - M); e.w = __expf(x.w - M);
    red[t] = act ? (e.x + e.y + e.z + e.w) : 0.f;
    __syncthreads();
    #pragma unroll
    for (int s = 128; s >= 1; s >>= 1) {
        if (t < s) red[t] += red[t + s];
        __syncthreads();
    }
    float inv = 1.0f / red[0];
    if (act) {
        float4 rr;
        rr.x = e.x * inv; rr.y = e.y * inv; rr.z = e.z * inv; rr.w = e.w * inv;
        *(float4*)&p[t * 4] = rr;
    }
}

extern "C" void kernel_launch(void* const* d_in, const int* in_sizes, int n_in,
                              void* d_out, int out_size, void* d_ws, size_t ws_size,
                              hipStream_t stream)
{
    const float* pref  = (const float*)d_in[0];
    const float* nodes = (const float*)d_in[1];
    const float* q1    = (const float*)d_in[2];
    const float* lastn = (const float*)d_in[3];
    const float* mask  = (const float*)d_in[4];
    const float* fc1_w = (const float*)d_in[5];
    const float* fc1_b = (const float*)d_in[6];
    const float* fc2_w = (const float*)d_in[7];
    const float* fc2_b = (const float*)d_in[8];
    const float* fc3_w = (const float*)d_in[9];
    const float* fc3_b = (const float*)d_in[10];
    const float* wqf   = (const float*)d_in[11];
    const float* wql   = (const float*)d_in[12];
    const float* wk    = (const float*)d_in[13];
    const float* wv    = (const float*)d_in[14];
    const float* wc    = (const float*)d_in[15];
    float* out = (float*)d_out;
    float* ws  = (float*)d_ws;

    float* W5 = ws;                                   // 5*16384 = 81920
    float* Kb = ws + 81920;                           // 8*1196*128
    float* Vb = Kb + (long)BB * NKEY * EMB;
    float* Qb = Vb + (long)BB * NKEY * EMB;           // 8*1000*128
    float* OC = Qb + (long)BB * POMO * EMB;
    float* MH = OC + (long)BB * POMO * EMB;           // ends at ~22.4 MB

    float* part = out;  // d_out (32 MB) as scratch for attention partials
                        // (fully overwritten by logits_kernel afterwards)

    hipLaunchKernelGGL(hyper_kernel, dim3(1), dim3(256), 0, stream,
                       pref, fc1_w, fc1_b, fc2_w, fc2_b, fc3_w, fc3_b,
                       wqf, wql, wk, wv, wc, W5);
    hipLaunchKernelGGL(kv_proj_kernel, dim3(299), dim3(256), 0, stream, nodes, W5, Kb, Vb);
    hipLaunchKernelGGL(q_proj_kernel, dim3(250), dim3(256), 0, stream, q1, lastn, W5, Qb);
    hipLaunchKernelGGL(attn_split_kernel, dim3(8, RTILES, SCH), dim3(128), 0, stream,
                       Kb, Vb, Qb, mask, part);
    hipLaunchKernelGGL(attn_merge_kernel, dim3(8, RTILES), dim3(256), 0, stream, part, OC);
    hipLaunchKernelGGL(combine_kernel, dim3(250), dim3(256), 0, stream, OC, W5, MH);
    hipLaunchKernelGGL(logits_kernel, dim3(8, 16, 16), dim3(256), 0, stream, MH, nodes, mask, out);
    hipLaunchKernelGGL(softmax_kernel, dim3(8000), dim3(256), 0, stream, out);
}

// Round 3
// 332.795 us; speedup vs baseline: 1.5551x; 1.1154x over previous
//
#include <hip/hip_runtime.h>
#include <math.h>

#define EMB 128
#define NH 8
#define DH 16
#define HID 256
#define NODE 1000
#define PATCH 196
#define NKEY (NODE + PATCH)   // 1196
#define BB 8
#define POMO 1000
#define KT 16                  // attention key tile
#define SCH 6                  // key-split chunks
#define CKEYS 200              // keys per chunk (last chunk = 196)
#define RTILES 32              // row tiles of 32 rows

// partial buffers (alias d_out, 8M floats):
// pacc: [b][tile][chunk][row32][h][16]  = 8*32*6*32*8*16 = 6,291,456 floats
// pml : [b][tile][chunk][h][row32][2]   = 8*32*6*8*32*2  =   786,432 floats
#define PACC_FLOATS 6291456L

__device__ __forceinline__ float tanh10(float x) {
    float e = __expf(2.0f * x);
    return 10.0f * (1.0f - 2.0f / (e + 1.0f));
}

// ---------------- hypernet: pref -> 5 weight matrices (128x128 each) --------
__global__ __launch_bounds__(256) void hyper_kernel(
    const float* __restrict__ pref,
    const float* __restrict__ fc1_w, const float* __restrict__ fc1_b,
    const float* __restrict__ fc2_w, const float* __restrict__ fc2_b,
    const float* __restrict__ fc3_w, const float* __restrict__ fc3_b,
    const float* __restrict__ wqf, const float* __restrict__ wql,
    const float* __restrict__ wk,  const float* __restrict__ wv,
    const float* __restrict__ wc,  float* __restrict__ W5)
{
    __shared__ float h1[HID];
    __shared__ float h2[HID];
    __shared__ float mid[16];
    int t = threadIdx.x;
    float p0 = pref[0], p1 = pref[1], p2 = pref[2];
    h1[t] = fc1_b[t] + p0 * fc1_w[t * 3 + 0] + p1 * fc1_w[t * 3 + 1] + p2 * fc1_w[t * 3 + 2];
    __syncthreads();
    {
        float s = fc2_b[t];
        for (int j = 0; j < HID; ++j) s += h1[j] * fc2_w[t * HID + j];
        h2[t] = s;
    }
    __syncthreads();
    if (t < 15) {
        float m = fc3_b[t];
        for (int j = 0; j < HID; ++j) m += h2[j] * fc3_w[t * HID + j];
        mid[t] = m;
    }
    __syncthreads();
    #pragma unroll
    for (int mat = 0; mat < 5; ++mat) {
        const float* w = (mat == 0) ? wqf : (mat == 1) ? wql : (mat == 2) ? wk : (mat == 3) ? wv : wc;
        float m0 = mid[mat * 3 + 0], m1 = mid[mat * 3 + 1], m2 = mid[mat * 3 + 2];
        for (int x = t; x < EMB * EMB; x += 256) {
            W5[mat * EMB * EMB + x] = m0 * w[x * 3 + 0] + m1 * w[x * 3 + 1] + m2 * w[x * 3 + 2];
        }
    }
}

// ---------------- K,V projection of encoded_nodes ---------------------------
__global__ __launch_bounds__(256) void kv_proj_kernel(
    const float* __restrict__ nodes, const float* __restrict__ W5,
    float* __restrict__ Kb, float* __restrict__ Vb)
{
    __shared__ float xs[32][EMB];
    int t = threadIdx.x;
    long r0 = (long)blockIdx.x * 32;            // over BB*NKEY = 9568 (299*32 exact)
    const float4* s4 = (const float4*)(nodes + r0 * EMB);
    float4* x4p = (float4*)&xs[0][0];
    for (int i = t; i < 32 * EMB / 4; i += 256) x4p[i] = s4[i];
    __syncthreads();
    int o = t;
    const float* W = (o < EMB) ? (W5 + 2 * EMB * EMB + o * EMB)
                               : (W5 + 3 * EMB * EMB + (o - EMB) * EMB);
    float acc[32];
    #pragma unroll
    for (int r = 0; r < 32; ++r) acc[r] = 0.f;
    for (int e = 0; e < EMB; e += 4) {
        float4 w4 = *(const float4*)&W[e];
        #pragma unroll
        for (int r = 0; r < 32; ++r) {
            float4 x4 = *(const float4*)&xs[r][e];
            acc[r] += x4.x * w4.x + x4.y * w4.y + x4.z * w4.z + x4.w * w4.w;
        }
    }
    float* dst = (o < EMB) ? (Kb + r0 * EMB + o) : (Vb + r0 * EMB + (o - EMB));
    #pragma unroll
    for (int r = 0; r < 32; ++r) dst[(long)r * EMB] = acc[r];
}

// ---------------- Q projection: q1@Wqf.T + last@Wql.T -----------------------
__global__ __launch_bounds__(256) void q_proj_kernel(
    const float* __restrict__ q1, const float* __restrict__ lastn,
    const float* __restrict__ W5, float* __restrict__ Qb)
{
    __shared__ float xa[32][EMB];
    __shared__ float xb[32][EMB];
    int t = threadIdx.x;
    long r0 = (long)blockIdx.x * 32;            // over 8000 (250*32 exact)
    const float4* a4 = (const float4*)(q1 + r0 * EMB);
    const float4* b4 = (const float4*)(lastn + r0 * EMB);
    float4* xap = (float4*)&xa[0][0];
    float4* xbp = (float4*)&xb[0][0];
    for (int i = t; i < 32 * EMB / 4; i += 256) { xap[i] = a4[i]; xbp[i] = b4[i]; }
    __syncthreads();
    int o = t & 127;
    int rbase = (t >> 7) * 16;
    const float* Wf = W5 + 0 * EMB * EMB + o * EMB;
    const float* Wl = W5 + 1 * EMB * EMB + o * EMB;
    float acc[16];
    #pragma unroll
    for (int r = 0; r < 16; ++r) acc[r] = 0.f;
    for (int e = 0; e < EMB; e += 4) {
        float4 wf = *(const float4*)&Wf[e];
        float4 wl = *(const float4*)&Wl[e];
        #pragma unroll
        for (int r = 0; r < 16; ++r) {
            float4 va = *(const float4*)&xa[rbase + r][e];
            float4 vb = *(const float4*)&xb[rbase + r][e];
            acc[r] += va.x * wf.x + va.y * wf.y + va.z * wf.z + va.w * wf.w
                    + vb.x * wl.x + vb.y * wl.y + vb.z * wl.z + vb.w * wl.w;
        }
    }
    #pragma unroll
    for (int r = 0; r < 16; ++r) Qb[(r0 + rbase + r) * EMB + o] = acc[r];
}

// ---------------- fused masked MHA, key-split flash -------------------------
// grid (8, 32, 6): x=b (XCD-aligned), y=32-row tile, z=key chunk.
// block 128: h = t>>4, rr = t&15; each thread owns rows {2rr, 2rr+1}.
// Dense 64B-record partials: no read-modify-write on any acc line.
__global__ __launch_bounds__(128, 3) void attn_split_kernel(
    const float* __restrict__ Kb, const float* __restrict__ Vb,
    const float* __restrict__ Qb, const float* __restrict__ mask,
    float* __restrict__ pacc, float* __restrict__ pml)
{
    __shared__ float ks[KT][EMB];
    __shared__ float vs[KT][EMB];
    int t = threadIdx.x;
    int b = blockIdx.x;
    int tile = blockIdx.y;
    int c = blockIdx.z;
    int rr = t & 15;
    int h = t >> 4;
    int row0 = tile * 32 + rr * 2;
    bool active = row0 < POMO;       // row0 even => row0+1 also < POMO when active
    int kstart = c * CKEYS;
    int kend = kstart + CKEYS; if (kend > NKEY) kend = NKEY;
    bool has_mask = (kstart < NODE); // chunks 0..4 node keys only, chunk 5 pure patch

    float q0[DH], q1r[DH], acc0[DH], acc1[DH];
    #pragma unroll
    for (int i = 0; i < DH; ++i) { q0[i] = 0.f; q1r[i] = 0.f; acc0[i] = 0.f; acc1[i] = 0.f; }
    if (active) {
        const float4* qp0 = (const float4*)(Qb + ((long)b * POMO + row0) * EMB + h * DH);
        const float4* qp1 = (const float4*)(Qb + ((long)b * POMO + row0 + 1) * EMB + h * DH);
        #pragma unroll
        for (int i = 0; i < 4; ++i) {
            float4 v = qp0[i];   // pre-scale by 1/sqrt(16) so score = q.k + mask
            q0[4*i+0] = v.x*0.25f; q0[4*i+1] = v.y*0.25f; q0[4*i+2] = v.z*0.25f; q0[4*i+3] = v.w*0.25f;
            float4 w = qp1[i];
            q1r[4*i+0] = w.x*0.25f; q1r[4*i+1] = w.y*0.25f; q1r[4*i+2] = w.z*0.25f; q1r[4*i+3] = w.w*0.25f;
        }
    }
    float m0_run = -1e30f, m1_run = -1e30f, l0 = 0.f, l1 = 0.f;

    for (int t0 = kstart; t0 < kend; t0 += KT) {
        int valid = kend - t0; if (valid > KT) valid = KT;
        __syncthreads();
        {   // stage K,V tile; clamp source index past kend (garbage keys get p=0)
            const float4* ksrc = (const float4*)(Kb + ((long)b * NKEY) * EMB);
            const float4* vsrc = (const float4*)(Vb + ((long)b * NKEY) * EMB);
            float4* kd = (float4*)&ks[0][0];
            float4* vd = (float4*)&vs[0][0];
            int base4 = t0 * (EMB / 4);
            int max4 = NKEY * (EMB / 4) - 1;
            for (int i = t; i < KT * EMB / 4; i += 128) {
                int src = base4 + i; if (src > max4) src = max4;
                kd[i] = ksrc[src];
                vd[i] = vsrc[src];
            }
        }
        __syncthreads();

        float sc0[KT], sc1[KT];
        // init scores with mask (global float4 reads; no LDS)
        if (has_mask && active) {
            const float4* mp0 = (const float4*)(mask + ((long)b * POMO + row0) * NODE + t0);
            const float4* mp1 = (const float4*)(mask + ((long)b * POMO + row0 + 1) * NODE + t0);
            int mv4 = valid >> 2;   // valid in {16,8}: whole float4s
            #pragma unroll
            for (int j4 = 0; j4 < KT / 4; ++j4) {
                float4 a = (j4 < mv4) ? mp0[j4] : make_float4(0,0,0,0);
                float4 bm = (j4 < mv4) ? mp1[j4] : make_float4(0,0,0,0);
                sc0[4*j4+0] = a.x;  sc0[4*j4+1] = a.y;  sc0[4*j4+2] = a.z;  sc0[4*j4+3] = a.w;
                sc1[4*j4+0] = bm.x; sc1[4*j4+1] = bm.y; sc1[4*j4+2] = bm.z; sc1[4*j4+3] = bm.w;
            }
        } else {
            #pragma unroll
            for (int j = 0; j < KT; ++j) { sc0[j] = 0.f; sc1[j] = 0.f; }
        }
        // scores: one K read serves both rows
        #pragma unroll
        for (int j = 0; j < KT; ++j) {
            float s0 = sc0[j], s1 = sc1[j];
            #pragma unroll
            for (int e = 0; e < DH; e += 4) {
                float4 k4 = *(const float4*)&ks[j][h * DH + e];
                s0 += q0[e]*k4.x + q0[e+1]*k4.y + q0[e+2]*k4.z + q0[e+3]*k4.w;
                s1 += q1r[e]*k4.x + q1r[e+1]*k4.y + q1r[e+2]*k4.z + q1r[e+3]*k4.w;
            }
            sc0[j] = (j < valid) ? s0 : -1e30f;
            sc1[j] = (j < valid) ? s1 : -1e30f;
        }
        float tm0 = sc0[0], tm1 = sc1[0];
        #pragma unroll
        for (int j = 1; j < KT; ++j) { tm0 = fmaxf(tm0, sc0[j]); tm1 = fmaxf(tm1, sc1[j]); }
        float nm0 = fmaxf(m0_run, tm0), nm1 = fmaxf(m1_run, tm1);
        if (__any((nm0 > m0_run) || (nm1 > m1_run))) {
            float s0f = __expf(m0_run - nm0), s1f = __expf(m1_run - nm1);
            l0 *= s0f; l1 *= s1f;
            #pragma unroll
            for (int d = 0; d < DH; ++d) { acc0[d] *= s0f; acc1[d] *= s1f; }
            m0_run = nm0; m1_run = nm1;
        }
        #pragma unroll
        for (int j = 0; j < KT; ++j) {
            float p0 = __expf(sc0[j] - m0_run);
            float p1 = __expf(sc1[j] - m1_run);
            l0 += p0; l1 += p1;
            #pragma unroll
            for (int e = 0; e < DH; e += 4) {
                float4 v4 = *(const float4*)&vs[j][h * DH + e];
                acc0[e+0] += p0*v4.x; acc0[e+1] += p0*v4.y; acc0[e+2] += p0*v4.z; acc0[e+3] += p0*v4.w;
                acc1[e+0] += p1*v4.x; acc1[e+1] += p1*v4.y; acc1[e+2] += p1*v4.z; acc1[e+3] += p1*v4.w;
            }
        }
    }
    if (active) {
        long cb = ((long)(b * RTILES + tile) * SCH + c);
        // acc: [cb][row32][h][16] -- 64B records, h-stride 64B: wave-dense
        long rec0 = ((cb * 32 + rr * 2) * NH + h) * 16;
        long rec1 = rec0 + (long)NH * 16;
        #pragma unroll
        for (int i = 0; i < 4; ++i) {
            *(float4*)&pacc[rec0 + 4*i] = make_float4(acc0[4*i], acc0[4*i+1], acc0[4*i+2], acc0[4*i+3]);
            *(float4*)&pacc[rec1 + 4*i] = make_float4(acc1[4*i], acc1[4*i+1], acc1[4*i+2], acc1[4*i+3]);
        }
        // ml: [cb][h][row32][2] -- h-major: each wave's writes are contiguous
        long mlrec = (cb * NH + h) * 32 + rr * 2;
        *(float2*)&pml[mlrec * 2] = make_float2(m0_run, l0);
        *(float2*)&pml[(mlrec + 1) * 2] = make_float2(m1_run, l1);
    }
}

// ---------------- merge key-split partials -> OC ----------------------------
__global__ __launch_bounds__(256) void attn_merge_kernel(
    const float* __restrict__ pacc, const float* __restrict__ pml,
    float* __restrict__ OC)
{
    int t = threadIdx.x;          // t = rt*8 + h
    int b = blockIdx.x, tile = blockIdx.y;
    int rt = t >> 3, h = t & 7;
    int row = tile * 32 + rt;
    if (row >= POMO) return;
    long cb0 = (long)(b * RTILES + tile) * SCH;
    const long cs_acc = 32L * NH * 16;   // acc chunk stride
    long abase = cb0 * cs_acc + ((long)rt * NH + h) * 16;
    const long cs_ml = (long)NH * 32;    // ml chunk stride (records)
    long mbase = (cb0 * NH + h) * 32 + rt;

    float mc[SCH], lc[SCH];
    float M = -1e30f;
    #pragma unroll
    for (int c = 0; c < SCH; ++c) {
        float2 ml = *(const float2*)&pml[(mbase + c * cs_ml) * 2];
        mc[c] = ml.x; lc[c] = ml.y;
        M = fmaxf(M, mc[c]);
    }
    float L = 0.f;
    float o[16];
    #pragma unroll
    for (int i = 0; i < 16; ++i) o[i] = 0.f;
    #pragma unroll
    for (int c = 0; c < SCH; ++c) {
        float w = __expf(mc[c] - M);
        L += lc[c] * w;
        #pragma unroll
        for (int i4 = 0; i4 < 4; ++i4) {
            float4 a = *(const float4*)&pacc[abase + c * cs_acc + 4 * i4];
            o[4*i4+0] += w*a.x; o[4*i4+1] += w*a.y; o[4*i4+2] += w*a.z; o[4*i4+3] += w*a.w;
        }
    }
    float inv = 1.0f / L;
    float* op = OC + ((long)b * POMO + row) * EMB + h * DH;
    #pragma unroll
    for (int i4 = 0; i4 < 4; ++i4)
        *(float4*)&op[4*i4] = make_float4(o[4*i4]*inv, o[4*i4+1]*inv, o[4*i4+2]*inv, o[4*i4+3]*inv);
}

// ---------------- multi-head combine: mh = oc @ Wc.T ------------------------
__global__ __launch_bounds__(256) void combine_kernel(
    const float* __restrict__ OC, const float* __restrict__ W5,
    float* __restrict__ MH)
{
    __shared__ float xs[32][EMB];
    int t = threadIdx.x;
    long r0 = (long)blockIdx.x * 32;            // over 8000
    const float4* s4 = (const float4*)(OC + r0 * EMB);
    float4* xp = (float4*)&xs[0][0];
    for (int i = t; i < 32 * EMB / 4; i += 256) xp[i] = s4[i];
    __syncthreads();
    int o = t & 127;
    int rbase = (t >> 7) * 16;
    const float* W = W5 + 4 * EMB * EMB + o * EMB;
    float acc[16];
    #pragma unroll
    for (int r = 0; r < 16; ++r) acc[r] = 0.f;
    for (int e = 0; e < EMB; e += 4) {
        float4 w4 = *(const float4*)&W[e];
        #pragma unroll
        for (int r = 0; r < 16; ++r) {
            float4 x4 = *(const float4*)&xs[rbase + r][e];
            acc[r] += x4.x * w4.x + x4.y * w4.y + x4.z * w4.z + x4.w * w4.w;
        }
    }
    #pragma unroll
    for (int r = 0; r < 16; ++r) MH[(r0 + rbase + r) * EMB + o] = acc[r];
}

// ---------------- logits: 10*tanh((mh @ nodes.T)/sqrt(128)) + mask ----------
__global__ __launch_bounds__(256) void logits_kernel(
    const float* __restrict__ MH, const float* __restrict__ nodes,
    const float* __restrict__ mask, float* __restrict__ out)
{
    __shared__ float As[64][65];   // [e][r]
    __shared__ float Bs[64][65];   // [e][c]
    int t = threadIdx.x;
    int b = blockIdx.x;
    int m0 = blockIdx.y * 64;
    int n0 = blockIdx.z * 64;
    int tc = t & 15, tr = t >> 4;
    float acc[4][4];
    #pragma unroll
    for (int i = 0; i < 4; ++i)
        #pragma unroll
        for (int j = 0; j < 4; ++j) acc[i][j] = 0.f;

    for (int e0 = 0; e0 < EMB; e0 += 64) {
        for (int i = t; i < 4096; i += 256) {
            int rr = i >> 6, e = i & 63;
            int n = n0 + rr;
            As[e][rr] = (n < POMO) ? MH[((long)b * POMO + n) * EMB + e0 + e] : 0.f;
        }
        for (int i = t; i < 4096; i += 256) {
            int cc = i >> 6, e = i & 63;
            Bs[e][cc] = nodes[((long)b * NKEY + m0 + cc) * EMB + e0 + e];
        }
        __syncthreads();
        for (int e = 0; e < 64; ++e) {
            float a0 = As[e][tr * 4 + 0], a1 = As[e][tr * 4 + 1];
            float a2 = As[e][tr * 4 + 2], a3 = As[e][tr * 4 + 3];
            float b0 = Bs[e][tc * 4 + 0], b1 = Bs[e][tc * 4 + 1];
            float b2 = Bs[e][tc * 4 + 2], b3 = Bs[e][tc * 4 + 3];
            acc[0][0] += a0 * b0; acc[0][1] += a0 * b1; acc[0][2] += a0 * b2; acc[0][3] += a0 * b3;
            acc[1][0] += a1 * b0; acc[1][1] += a1 * b1; acc[1][2] += a1 * b2; acc[1][3] += a1 * b3;
            acc[2][0] += a2 * b0; acc[2][1] += a2 * b1; acc[2][2] += a2 * b2; acc[2][3] += a2 * b3;
            acc[3][0] += a3 * b0; acc[3][1] += a3 * b1; acc[3][2] += a3 * b2; acc[3][3] += a3 * b3;
        }
        __syncthreads();
    }
    const float inv = 0.08838834764831845f;  // 1/sqrt(128)
    #pragma unroll
    for (int i = 0; i < 4; ++i) {
        int n = n0 + tr * 4 + i;
        if (n >= POMO) continue;
        #pragma unroll
        for (int j = 0; j < 4; ++j) {
            int m = m0 + tc * 4 + j;
            if (m >= NODE) continue;
            long idx = ((long)b * POMO + n) * NODE + m;
            out[idx] = tanh10(acc[i][j] * inv) + mask[idx];
        }
    }
}

// ---------------- in-place row softmax over 1000 ----------------------------
__global__ __launch_bounds__(256) void softmax_kernel(float* __restrict__ out)
{
    __shared__ float red[256];
    int t = threadIdx.x;
    float* p = out + (long)blockIdx.x * NODE;
    bool act = t < 250;
    float4 x = make_float4(0.f, 0.f, 0.f, 0.f);
    if (act) x = *(const float4*)&p[t * 4];
    float mx = act ? fmaxf(fmaxf(x.x, x.y), fmaxf(x.z, x.w)) : -1e30f;
    red[t] = mx;
    __syncthreads();
    #pragma unroll
    for (int s = 128; s >= 1; s >>= 1) {
        if (t < s) red[t] = fmaxf(red[t], red[t + s]);
        __syncthreads();
    }
    float M = red[0];
    __syncthreads();
    float4 e;
    e.x = __expf(x.x - M); e.y = __expf(x.y - M);
    e.z = __expf(x.z - M); e.w = __expf(x.w - M);
    red[t] = act ? (e.x + e.y + e.z + e.w) : 0.f;
    __syncthreads();
    #pragma unroll
    for (int s = 128; s >= 1; s >>= 1) {
        if (t < s) red[t] += red[t + s];
        __syncthreads();
    }
    float inv = 1.0f / red[0];
    if (act) {
        float4 rr;
        rr.x = e.x * inv; rr.y = e.y * inv; rr.z = e.z * inv; rr.w = e.w * inv;
        *(float4*)&p[t * 4] = rr;
    }
}

extern "C" void kernel_launch(void* const* d_in, const int* in_sizes, int n_in,
                              void* d_out, int out_size, void* d_ws, size_t ws_size,
                              hipStream_t stream)
{
    const float* pref  = (const float*)d_in[0];
    const float* nodes = (const float*)d_in[1];
    const float* q1    = (const float*)d_in[2];
    const float* lastn = (const float*)d_in[3];
    const float* mask  = (const float*)d_in[4];
    const float* fc1_w = (const float*)d_in[5];
    const float* fc1_b = (const float*)d_in[6];
    const float* fc2_w = (const float*)d_in[7];
    const float* fc2_b = (const float*)d_in[8];
    const float* fc3_w = (const float*)d_in[9];
    const float* fc3_b = (const float*)d_in[10];
    const float* wqf   = (const float*)d_in[11];
    const float* wql   = (const float*)d_in[12];
    const float* wk    = (const float*)d_in[13];
    const float* wv    = (const float*)d_in[14];
    const float* wc    = (const float*)d_in[15];
    float* out = (float*)d_out;
    float* ws  = (float*)d_ws;

    float* W5 = ws;                                   // 5*16384 = 81920
    float* Kb = ws + 81920;                           // 8*1196*128
    float* Vb = Kb + (long)BB * NKEY * EMB;
    float* Qb = Vb + (long)BB * NKEY * EMB;           // 8*1000*128
    float* OC = Qb + (long)BB * POMO * EMB;
    float* MH = OC + (long)BB * POMO * EMB;           // ends at ~22.4 MB

    float* pacc = out;                 // d_out (32 MB) as partial scratch
    float* pml  = out + PACC_FLOATS;   // fully overwritten by logits later

    hipLaunchKernelGGL(hyper_kernel, dim3(1), dim3(256), 0, stream,
                       pref, fc1_w, fc1_b, fc2_w, fc2_b, fc3_w, fc3_b,
                       wqf, wql, wk, wv, wc, W5);
    hipLaunchKernelGGL(kv_proj_kernel, dim3(299), dim3(256), 0, stream, nodes, W5, Kb, Vb);
    hipLaunchKernelGGL(q_proj_kernel, dim3(250), dim3(256), 0, stream, q1, lastn, W5, Qb);
    hipLaunchKernelGGL(attn_split_kernel, dim3(8, RTILES, SCH), dim3(128), 0, stream,
                       Kb, Vb, Qb, mask, pacc, pml);
    hipLaunchKernelGGL(attn_merge_kernel, dim3(8, RTILES), dim3(256), 0, stream, pacc, pml, OC);
    hipLaunchKernelGGL(combine_kernel, dim3(250), dim3(256), 0, stream, OC, W5, MH);
    hipLaunchKernelGGL(logits_kernel, dim3(8, 16, 16), dim3(256), 0, stream, MH, nodes, mask, out);
    hipLaunchKernelGGL(softmax_kernel, dim3(8000), dim3(256), 0, stream, out);
}